// Round 10
// baseline (205.571 us; speedup 1.0000x reference)
//
#include <hip/hip_runtime.h>
#include <hip/hip_bf16.h>
#include <math.h>

#define B_N   2000
#define T_N   32
#define CIN_N 32
#define COUT_N 128
#define E_N   32000
#define NEG_S 0.01f
#define EPS_S 1e-5f
#define NNODE (B_N * T_N)   // 64000
#define EPAD_N 38016        // padded CSR capacity (multiple-of-4 per node)
// contiguous meta region: deg(2000)+cnt(2000)+cursor(2000)+offs(2004)+csr_src(38016)+csr_norm(38016)
#define META_I4 21009       // 336144 B = 21009 int4

typedef __attribute__((ext_vector_type(8))) __bf16 bf16x8;
typedef __attribute__((ext_vector_type(4))) float f32x4;
typedef __attribute__((ext_vector_type(8))) unsigned short u16x8;

__device__ __forceinline__ unsigned short f2bf(float f) {
  unsigned u = __builtin_bit_cast(unsigned, f);
  u += 0x7FFFu + ((u >> 16) & 1u);   // RNE (finite values)
  return (unsigned short)(u >> 16);
}
__device__ __forceinline__ float bf2f(unsigned short h) {
  unsigned u = ((unsigned)h) << 16;
  return __builtin_bit_cast(float, u);
}

// ---------------- Kernel P: fused prep — zero meta + cast both weight tensors ----------------
// wBc[((nf2*3+ks)*64+lane)*8+e]  = cw[col*96+k],            col=nf2*16+(lane&15), k=ks*32+(lane>>4)*8+e
// wB [((nf2*12+ks)*64+lane)*8+e] = tag_w[k>>7][k&127][col], same lane mapping, K=384
__global__ __launch_bounds__(256) void k_prep(
    const float* __restrict__ cw, const float* __restrict__ tw,
    unsigned short* __restrict__ wBc, unsigned short* __restrict__ wB,
    int4* __restrict__ meta)
{
  const int tid0 = blockIdx.x * 256 + threadIdx.x;
  const int stride = gridDim.x * 256;
  const int4 z = {0, 0, 0, 0};
  for (int i = tid0; i < META_I4; i += stride) meta[i] = z;
  for (int idx = tid0; idx < 12288; idx += stride) {
    int e = idx & 7, lane = (idx >> 3) & 63, rest = idx >> 9;
    int ks = rest % 3, nf2 = rest / 3;
    int col = nf2 * 16 + (lane & 15);
    int k = ks * 32 + ((lane >> 4) << 3) + e;
    wBc[idx] = f2bf(cw[col * 96 + k]);
  }
  for (int idx = tid0; idx < 49152; idx += stride) {
    int e = idx & 7, lane = (idx >> 3) & 63, rest = idx >> 9;
    int ks = rest % 12, nf2 = rest / 12;
    int col = nf2 * 16 + (lane & 15);
    int k = ks * 32 + ((lane >> 4) << 3) + e;
    wB[idx] = f2bf(tw[(k >> 7) * 16384 + (k & 127) * 128 + col]);
  }
}

// ---------------- Kernel 1: FUSED causal-conv (MFMA) + bias + LeakyReLU + LayerNorm ----------
// Block = 4 samples x 2 waves; wave = 16 timesteps (t0=0/16) x 128 cols of one sample b.
// x staged in LDS, A-frags built in-register, LN via cross-wave LDS reduction.
__global__ __launch_bounds__(512, 4) void k_convln(
    const float* __restrict__ x, const unsigned short* __restrict__ wBc,
    const float* __restrict__ cb, const float* __restrict__ gamma,
    const float* __restrict__ beta, unsigned short* __restrict__ xcat)
{
  __shared__ unsigned short sB[12288];   // 24KB conv weights, frag-order
  __shared__ float sx4[4][1088];         // 17KB: per-sample im2col source, sx4[s][ci*34+t+2]
  __shared__ float red1[8], red2[8];
  const int tid = threadIdx.x;
  const int w = tid >> 6, lane = tid & 63;
  const int s = w >> 1;                       // sample slot 0..3
  const int b = blockIdx.x * 4 + s;
  const int t0 = (w & 1) * 16;
  const int r = lane & 15, q = lane >> 4;

  #pragma unroll
  for (int i = 0; i < 3; ++i) {
    int id = i * 512 + tid;                   // 1536 float4
    ((float4*)sB)[id] = ((const float4*)wBc)[id];
  }
  for (int idx = tid; idx < 4 * 1088; idx += 512) {
    int ss = idx >> 10 ? idx / 1088 : 0;      // compute cleanly below
    ss = idx / 1088;
    int rem = idx - ss * 1088;
    int ci = rem / 34, tt = rem - ci * 34;
    sx4[ss][rem] = (tt >= 2) ? x[(blockIdx.x * 4 + ss) * 1024 + ci * 32 + (tt - 2)] : 0.f;
  }
  __syncthreads();

  // build 3 A-fragments from LDS: A[t][k], t = t0+r, k = ks*32 + q*8 + e
  const int ta = t0 + r;
  u16x8 a_[3];
  #pragma unroll
  for (int ks = 0; ks < 3; ++ks) {
    #pragma unroll
    for (int e = 0; e < 8; ++e) {
      int k = ks * 32 + q * 8 + e;
      int ci = k / 3, kk = k - ci * 3;
      a_[ks][e] = f2bf(sx4[s][ci * 34 + ta + kk]);
    }
  }

  f32x4 acc[8] = {};
  #pragma unroll
  for (int ks = 0; ks < 3; ++ks) {
    bf16x8 a = __builtin_bit_cast(bf16x8, a_[ks]);
    #pragma unroll
    for (int nf = 0; nf < 8; ++nf) {
      bf16x8 bv = *(const bf16x8*)&sB[((nf * 3 + ks) * 64 + lane) * 8];
      acc[nf] = __builtin_amdgcn_mfma_f32_16x16x32_bf16(a, bv, acc[nf], 0, 0, 0);
    }
  }

  // bias + LeakyReLU in place; accumulate LN partials
  float s1 = 0.f, s2 = 0.f;
  #pragma unroll
  for (int nf = 0; nf < 8; ++nf) {
    const float bias = cb[nf * 16 + r];
    #pragma unroll
    for (int i = 0; i < 4; ++i) {
      float u = acc[nf][i] + bias;
      u = (u >= 0.f) ? u : NEG_S * u;
      acc[nf][i] = u;
      s1 += u; s2 += u * u;
    }
  }
  #pragma unroll
  for (int d = 32; d > 0; d >>= 1) {
    s1 += __shfl_down(s1, d);
    s2 += __shfl_down(s2, d);
  }
  if (lane == 0) { red1[w] = s1; red2[w] = s2; }
  __syncthreads();
  const float a1 = red1[w & ~1] + red1[w | 1];
  const float a2 = red2[w & ~1] + red2[w | 1];
  const float mu = a1 / 4096.f;
  const float rs = rsqrtf(a2 / 4096.f - mu * mu + EPS_S);

  // normalize + affine, write bf16 xcat cols 0..127
  #pragma unroll
  for (int nf = 0; nf < 8; ++nf) {
    const int col = nf * 16 + r;
    #pragma unroll
    for (int i = 0; i < 4; ++i) {
      const int t = t0 + q * 4 + i;
      float v = (acc[nf][i] - mu) * rs * gamma[col * 32 + t] + beta[col * 32 + t];
      xcat[(size_t)(t * B_N + b) * 384 + col] = f2bf(v);
    }
  }
}

// ---------------- Kernel 2: in-degree (weighted) + in-edge counts ----------------
__global__ void k_deg(const int* __restrict__ ei, const float* __restrict__ ew,
                      float* __restrict__ deg, int* __restrict__ cnt)
{
  int e = blockIdx.x * 256 + threadIdx.x;
  if (e >= E_N) return;
  int d = ei[E_N + e];
  atomicAdd(&deg[d], ew[e]);
  atomicAdd(&cnt[d], 1);
}

// ---------------- Kernel 3: single-block exclusive scan over 2000 PADDED counts ----------------
__global__ __launch_bounds__(256) void k_scan(const int* __restrict__ cnt, int* __restrict__ offs)
{
  __shared__ int wsum[4];
  int tid = threadIdx.x;
  int vals[8];
  int run = 0;
  #pragma unroll
  for (int i = 0; i < 8; ++i) {
    int idx = tid * 8 + i;
    vals[i] = run;
    int v = (idx < B_N) ? cnt[idx] : 0;
    v = (v + 3) & ~3;                       // pad to multiple of 4
    run += v;
  }
  int lane = tid & 63, wid = tid >> 6;
  int xs = run;
  #pragma unroll
  for (int d = 1; d < 64; d <<= 1) {
    int y = __shfl_up(xs, d);
    if (lane >= d) xs += y;
  }
  if (lane == 63) wsum[wid] = xs;
  __syncthreads();
  int pre = 0;
  for (int w = 0; w < wid; ++w) pre += wsum[w];
  int excl = pre + xs - run;
  #pragma unroll
  for (int i = 0; i < 8; ++i) {
    int idx = tid * 8 + i;
    if (idx <= B_N) offs[idx] = excl + vals[i];
  }
}

// ---------------- Kernel 4: CSR scatter + edge norm (pad slots stay {src=0, norm=0}) ----------------
__global__ void k_scatter(const int* __restrict__ ei, const float* __restrict__ ew,
                          const float* __restrict__ deg, const int* __restrict__ offs,
                          int* __restrict__ cursor, int* __restrict__ csr_src,
                          float* __restrict__ csr_norm)
{
  int e = blockIdx.x * 256 + threadIdx.x;
  if (e >= E_N) return;
  int s = ei[e], d = ei[E_N + e];
  float ds_ = deg[s], dd = deg[d];
  float dis_s = (ds_ > 0.f) ? rsqrtf(fmaxf(ds_, 1e-12f)) : 0.f;
  float dis_d = (dd  > 0.f) ? rsqrtf(fmaxf(dd,  1e-12f)) : 0.f;
  float nrm = dis_s * ew[e] * dis_d;
  int pos = offs[d] + atomicAdd(&cursor[d], 1);
  csr_src[pos] = s;
  csr_norm[pos] = nrm;
}

// ---------------- Kernel 5: one-hop propagation, 4-t batched (t, t+8, t+16, t+24) ----------------
// 1 wave per (b, tp), tp in 0..7. 16000 waves. 16 independent gathers in flight per 4 edges.
__global__ __launch_bounds__(256) void k_prop(
    unsigned short* xcat, int cin, int cout_,
    const int* __restrict__ offs, const int* __restrict__ csr_src,
    const float* __restrict__ csr_norm)
{
  int gw = (blockIdx.x * 256 + threadIdx.x) >> 6;
  int lane = threadIdx.x & 63;
  if (gw >= B_N * 8) return;
  int tp = gw / B_N;                 // 0..7
  int b  = gw - tp * B_N;
  int beg = offs[b], end = offs[b + 1];           // both multiples of 4
  const unsigned short* base0 = xcat + (size_t)tp * B_N * 384 + cin + lane * 2;
  const size_t tstride = (size_t)8 * B_N * 384;
  const unsigned short* base[4] = {base0, base0 + tstride, base0 + 2 * tstride, base0 + 3 * tstride};
  float accx[4][4] = {};
  float accy[4][4] = {};
  for (int i = beg; i < end; i += 4) {
    int4   s4 = *(const int4*)&csr_src[i];
    float4 n4 = *(const float4*)&csr_norm[i];
    const size_t off[4] = {(size_t)s4.x * 384, (size_t)s4.y * 384,
                           (size_t)s4.z * 384, (size_t)s4.w * 384};
    const float nm[4] = {n4.x, n4.y, n4.z, n4.w};
    #pragma unroll
    for (int j = 0; j < 4; ++j) {
      #pragma unroll
      for (int e = 0; e < 4; ++e) {
        ushort2 v = *(const ushort2*)(base[j] + off[e]);
        accx[j][e] += nm[e] * bf2f(v.x);
        accy[j][e] += nm[e] * bf2f(v.y);
      }
    }
  }
  #pragma unroll
  for (int j = 0; j < 4; ++j) {
    float ax = (accx[j][0] + accx[j][1]) + (accx[j][2] + accx[j][3]);
    float ay = (accy[j][0] + accy[j][1]) + (accy[j][2] + accy[j][3]);
    ushort2 o; o.x = f2bf(ax); o.y = f2bf(ay);
    *(ushort2*)&xcat[(size_t)((tp + 8 * j) * B_N + b) * 384 + cout_ + lane * 2] = o;
  }
}

// ---------------- Kernel 6: MFMA triple-GEMM (K=384) + epilogue, direct [b][c][t] store ---------
// Wave M-tile = 16 timesteps of ONE sample b (thalf selects t0=0/16); cols 64 per chalf.
// Block = 8 waves = 8 consecutive b. Grid 1000 = 250 b-oct x {thalf,chalf}.
__global__ __launch_bounds__(512, 4) void k_gemm(
    const unsigned short* __restrict__ xcat, const unsigned short* __restrict__ wB,
    const float* __restrict__ tb, float* __restrict__ out)
{
  __shared__ unsigned short sB[24576];   // 48KB: 64 cols x 384 K, fragment-ordered
  const int tid = threadIdx.x;
  const int w = tid >> 6, lane = tid & 63;
  const int sel = blockIdx.x / 250;                  // 0..3
  const int b = (blockIdx.x % 250) * 8 + w;
  const int thalf = sel & 1, chalf = sel >> 1;
  const int t0 = thalf * 16;
  const int r = lane & 15, q = lane >> 4;

  const bf16x8* arow = (const bf16x8*)(xcat + (size_t)((t0 + r) * B_N + b) * 384 + q * 8);
  bf16x8 a[12];
  #pragma unroll
  for (int ks = 0; ks < 12; ++ks) a[ks] = arow[ks * 4];

  const float4* gB = (const float4*)(wB + (size_t)chalf * 24576);
  #pragma unroll
  for (int i = 0; i < 6; ++i) {
    int id = i * 512 + tid;
    ((float4*)sB)[id] = gB[id];
  }
  __syncthreads();

  f32x4 acc[4] = {};
  #pragma unroll
  for (int ks = 0; ks < 12; ++ks) {
    #pragma unroll
    for (int nf = 0; nf < 4; ++nf) {
      bf16x8 bv = *(const bf16x8*)&sB[((nf * 12 + ks) * 64 + lane) * 8];
      acc[nf] = __builtin_amdgcn_mfma_f32_16x16x32_bf16(a[ks], bv, acc[nf], 0, 0, 0);
    }
  }

  #pragma unroll
  for (int nf = 0; nf < 4; ++nf) {
    const int col = chalf * 64 + nf * 16 + r;
    const float bias = tb[col];
    float4 o;
    #pragma unroll
    for (int i = 0; i < 4; ++i) {
      const int t = t0 + q * 4 + i;
      float u = acc[nf][i] + bias;
      u = (u >= 0.f) ? u : NEG_S * u;
      float xv = bf2f(xcat[(size_t)(t * B_N + b) * 384 + col]);   // residual = xp
      ((float*)&o)[i] = xv + u;
    }
    *(float4*)&out[(size_t)b * 4096 + col * 32 + t0 + q * 4] = o;
  }
}

extern "C" void kernel_launch(void* const* d_in, const int* in_sizes, int n_in,
                              void* d_out, int out_size, void* d_ws, size_t ws_size,
                              hipStream_t stream)
{
  const float* x     = (const float*)d_in[0];
  const int*   ei    = (const int*)d_in[1];
  const float* ew    = (const float*)d_in[2];
  const float* cw    = (const float*)d_in[3];
  const float* cb    = (const float*)d_in[4];
  const float* gamma = (const float*)d_in[5];
  const float* beta  = (const float*)d_in[6];
  const float* tw    = (const float*)d_in[7];
  const float* tb    = (const float*)d_in[8];
  float* out = (float*)d_out;

  // workspace layout
  unsigned short* xcat = (unsigned short*)d_ws;                 // 64000*384 bf16
  float* deg = (float*)(xcat + (size_t)NNODE * 384);            // 2000 (16B aligned)
  int*   cnt    = (int*)(deg + B_N);                            // 2000
  int*   cursor = cnt + B_N;                                    // 2000
  int*   offs   = cursor + B_N;                                 // 2004 (padded for 16B align)
  int*   csr_src = offs + (B_N + 4);                            // EPAD_N
  float* csr_norm = (float*)(csr_src + EPAD_N);                 // EPAD_N
  unsigned short* wBc = (unsigned short*)(csr_norm + EPAD_N);   // 12288 bf16 frag-order
  unsigned short* wB  = wBc + 12288;                            // 49152 bf16 frag-order

  k_prep<<<96, 256, 0, stream>>>(cw, tw, wBc, wB, (int4*)deg);
  k_convln<<<500, 512, 0, stream>>>(x, wBc, cb, gamma, beta, xcat);
  k_deg<<<(E_N + 255) / 256, 256, 0, stream>>>(ei, ew, deg, cnt);
  k_scan<<<1, 256, 0, stream>>>(cnt, offs);
  k_scatter<<<(E_N + 255) / 256, 256, 0, stream>>>(ei, ew, deg, offs, cursor, csr_src, csr_norm);
  k_prop<<<B_N * 8 / 4, 256, 0, stream>>>(xcat, 0, 128, offs, csr_src, csr_norm);
  k_prop<<<B_N * 8 / 4, 256, 0, stream>>>(xcat, 128, 256, offs, csr_src, csr_norm);
  k_gemm<<<1000, 512, 0, stream>>>(xcat, wB, tb, out);
}

// Round 11
// 123.378 us; speedup vs baseline: 1.6662x; 1.6662x over previous
//
#include <hip/hip_runtime.h>
#include <hip/hip_bf16.h>
#include <math.h>

#define B_N   2000
#define T_N   32
#define CIN_N 32
#define COUT_N 128
#define E_N   32000
#define NEG_S 0.01f
#define EPS_S 1e-5f
#define NNODE (B_N * T_N)   // 64000
#define EPAD_N 38016        // padded CSR capacity (multiple-of-4 per node)
// contiguous meta region: deg(2000)+cnt(2000)+cursor(2000)+offs(2004)+csr_src(38016)+csr_norm(38016)
#define META_I4 21009       // 336144 B = 21009 int4

typedef __attribute__((ext_vector_type(8))) __bf16 bf16x8;
typedef __attribute__((ext_vector_type(4))) float f32x4;
typedef __attribute__((ext_vector_type(8))) unsigned short u16x8;

__device__ __forceinline__ unsigned short f2bf(float f) {
  unsigned u = __builtin_bit_cast(unsigned, f);
  u += 0x7FFFu + ((u >> 16) & 1u);   // RNE (finite values)
  return (unsigned short)(u >> 16);
}
__device__ __forceinline__ float bf2f(unsigned short h) {
  unsigned u = ((unsigned)h) << 16;
  return __builtin_bit_cast(float, u);
}

// ---------------- Kernel P: fused prep — zero meta + cast both weight tensors ----------------
// wBc[((nf2*3+ks)*64+lane)*8+e]  = cw[col*96+k],            col=nf2*16+(lane&15), k=ks*32+(lane>>4)*8+e
// wB [((nf2*12+ks)*64+lane)*8+e] = tag_w[k>>7][k&127][col], same lane mapping, K=384
__global__ __launch_bounds__(256) void k_prep(
    const float* __restrict__ cw, const float* __restrict__ tw,
    unsigned short* __restrict__ wBc, unsigned short* __restrict__ wB,
    int4* __restrict__ meta)
{
  const int tid0 = blockIdx.x * 256 + threadIdx.x;
  const int stride = gridDim.x * 256;
  const int4 z = {0, 0, 0, 0};
  for (int i = tid0; i < META_I4; i += stride) meta[i] = z;
  for (int idx = tid0; idx < 12288; idx += stride) {
    int e = idx & 7, lane = (idx >> 3) & 63, rest = idx >> 9;
    int ks = rest % 3, nf2 = rest / 3;
    int col = nf2 * 16 + (lane & 15);
    int k = ks * 32 + ((lane >> 4) << 3) + e;
    wBc[idx] = f2bf(cw[col * 96 + k]);
  }
  for (int idx = tid0; idx < 49152; idx += stride) {
    int e = idx & 7, lane = (idx >> 3) & 63, rest = idx >> 9;
    int ks = rest % 12, nf2 = rest / 12;
    int col = nf2 * 16 + (lane & 15);
    int k = ks * 32 + ((lane >> 4) << 3) + e;
    wB[idx] = f2bf(tw[(k >> 7) * 16384 + (k & 127) * 128 + col]);
  }
}

// ---------------- Kernel 1: FUSED causal-conv (MFMA) + bias + LeakyReLU + LayerNorm ----------
// Block = 4 samples x 2 waves; wave = 16 timesteps (t0=0/16) x 128 cols of one sample b.
__global__ __launch_bounds__(512, 4) void k_convln(
    const float* __restrict__ x, const unsigned short* __restrict__ wBc,
    const float* __restrict__ cb, const float* __restrict__ gamma,
    const float* __restrict__ beta, unsigned short* __restrict__ xcat)
{
  __shared__ unsigned short sB[12288];   // 24KB conv weights, frag-order
  __shared__ float sx4[4][1088];         // 17KB: per-sample im2col source, sx4[s][ci*34+t+2]
  __shared__ float red1[8], red2[8];
  const int tid = threadIdx.x;
  const int w = tid >> 6, lane = tid & 63;
  const int s = w >> 1;                       // sample slot 0..3
  const int b = blockIdx.x * 4 + s;
  const int t0 = (w & 1) * 16;
  const int r = lane & 15, q = lane >> 4;

  #pragma unroll
  for (int i = 0; i < 3; ++i) {
    int id = i * 512 + tid;                   // 1536 float4
    ((float4*)sB)[id] = ((const float4*)wBc)[id];
  }
  for (int idx = tid; idx < 4 * 1088; idx += 512) {
    int ss = idx / 1088;
    int rem = idx - ss * 1088;
    int ci = rem / 34, tt = rem - ci * 34;
    sx4[ss][rem] = (tt >= 2) ? x[(blockIdx.x * 4 + ss) * 1024 + ci * 32 + (tt - 2)] : 0.f;
  }
  __syncthreads();

  // build 3 A-fragments from LDS: A[t][k], t = t0+r, k = ks*32 + q*8 + e
  const int ta = t0 + r;
  u16x8 a_[3];
  #pragma unroll
  for (int ks = 0; ks < 3; ++ks) {
    #pragma unroll
    for (int e = 0; e < 8; ++e) {
      int k = ks * 32 + q * 8 + e;
      int ci = k / 3, kk = k - ci * 3;
      a_[ks][e] = f2bf(sx4[s][ci * 34 + ta + kk]);
    }
  }

  f32x4 acc[8] = {};
  #pragma unroll
  for (int ks = 0; ks < 3; ++ks) {
    bf16x8 a = __builtin_bit_cast(bf16x8, a_[ks]);
    #pragma unroll
    for (int nf = 0; nf < 8; ++nf) {
      bf16x8 bv = *(const bf16x8*)&sB[((nf * 3 + ks) * 64 + lane) * 8];
      acc[nf] = __builtin_amdgcn_mfma_f32_16x16x32_bf16(a, bv, acc[nf], 0, 0, 0);
    }
  }

  // bias + LeakyReLU in place; accumulate LN partials
  float s1 = 0.f, s2 = 0.f;
  #pragma unroll
  for (int nf = 0; nf < 8; ++nf) {
    const float bias = cb[nf * 16 + r];
    #pragma unroll
    for (int i = 0; i < 4; ++i) {
      float u = acc[nf][i] + bias;
      u = (u >= 0.f) ? u : NEG_S * u;
      acc[nf][i] = u;
      s1 += u; s2 += u * u;
    }
  }
  #pragma unroll
  for (int d = 32; d > 0; d >>= 1) {
    s1 += __shfl_down(s1, d);
    s2 += __shfl_down(s2, d);
  }
  if (lane == 0) { red1[w] = s1; red2[w] = s2; }
  __syncthreads();
  const float a1 = red1[w & ~1] + red1[w | 1];
  const float a2 = red2[w & ~1] + red2[w | 1];
  const float mu = a1 / 4096.f;
  const float rs = rsqrtf(a2 / 4096.f - mu * mu + EPS_S);

  // normalize + affine, write bf16 xcat cols 0..127
  #pragma unroll
  for (int nf = 0; nf < 8; ++nf) {
    const int col = nf * 16 + r;
    #pragma unroll
    for (int i = 0; i < 4; ++i) {
      const int t = t0 + q * 4 + i;
      float v = (acc[nf][i] - mu) * rs * gamma[col * 32 + t] + beta[col * 32 + t];
      xcat[(size_t)(t * B_N + b) * 384 + col] = f2bf(v);
    }
  }
}

// ---------------- Kernel 2: in-degree (weighted) + in-edge counts ----------------
__global__ void k_deg(const int* __restrict__ ei, const float* __restrict__ ew,
                      float* __restrict__ deg, int* __restrict__ cnt)
{
  int e = blockIdx.x * 256 + threadIdx.x;
  if (e >= E_N) return;
  int d = ei[E_N + e];
  atomicAdd(&deg[d], ew[e]);
  atomicAdd(&cnt[d], 1);
}

// ---------------- Kernel 3: single-block exclusive scan over 2000 PADDED counts ----------------
__global__ __launch_bounds__(256) void k_scan(const int* __restrict__ cnt, int* __restrict__ offs)
{
  __shared__ int wsum[4];
  int tid = threadIdx.x;
  int vals[8];
  int run = 0;
  #pragma unroll
  for (int i = 0; i < 8; ++i) {
    int idx = tid * 8 + i;
    vals[i] = run;
    int v = (idx < B_N) ? cnt[idx] : 0;
    v = (v + 3) & ~3;                       // pad to multiple of 4
    run += v;
  }
  int lane = tid & 63, wid = tid >> 6;
  int xs = run;
  #pragma unroll
  for (int d = 1; d < 64; d <<= 1) {
    int y = __shfl_up(xs, d);
    if (lane >= d) xs += y;
  }
  if (lane == 63) wsum[wid] = xs;
  __syncthreads();
  int pre = 0;
  for (int w = 0; w < wid; ++w) pre += wsum[w];
  int excl = pre + xs - run;
  #pragma unroll
  for (int i = 0; i < 8; ++i) {
    int idx = tid * 8 + i;
    if (idx <= B_N) offs[idx] = excl + vals[i];
  }
}

// ---------------- Kernel 4: CSR scatter + edge norm (pad slots stay {src=0, norm=0}) ----------------
__global__ void k_scatter(const int* __restrict__ ei, const float* __restrict__ ew,
                          const float* __restrict__ deg, const int* __restrict__ offs,
                          int* __restrict__ cursor, int* __restrict__ csr_src,
                          float* __restrict__ csr_norm)
{
  int e = blockIdx.x * 256 + threadIdx.x;
  if (e >= E_N) return;
  int s = ei[e], d = ei[E_N + e];
  float ds_ = deg[s], dd = deg[d];
  float dis_s = (ds_ > 0.f) ? rsqrtf(fmaxf(ds_, 1e-12f)) : 0.f;
  float dis_d = (dd  > 0.f) ? rsqrtf(fmaxf(dd,  1e-12f)) : 0.f;
  float nrm = dis_s * ew[e] * dis_d;
  int pos = offs[d] + atomicAdd(&cursor[d], 1);
  csr_src[pos] = s;
  csr_norm[pos] = nrm;
}

// ---------------- Kernel 5: one-hop propagation, t-paired (t and t+16) + 4-wide unroll ----------
// 1 wave per (b, tpair). 32000 waves. Reads cols [cin,cin+128), writes [cout_,cout_+128).
// NOTE: 4-t batching (r10) thrashed L2 (FETCH 74MB, 70us). Keep 2 slices/wave.
__global__ __launch_bounds__(256) void k_prop(
    unsigned short* xcat, int cin, int cout_,
    const int* __restrict__ offs, const int* __restrict__ csr_src,
    const float* __restrict__ csr_norm)
{
  int gw = (blockIdx.x * 256 + threadIdx.x) >> 6;
  int lane = threadIdx.x & 63;
  if (gw >= B_N * 16) return;
  int tp = gw / B_N;                 // 0..15
  int b  = gw - tp * B_N;
  int beg = offs[b], end = offs[b + 1];           // both multiples of 4
  const unsigned short* base0 = xcat + (size_t)tp * B_N * 384 + cin + lane * 2;
  const unsigned short* base1 = base0 + (size_t)16 * B_N * 384;
  float ax0 = 0.f, ay0 = 0.f, ax1 = 0.f, ay1 = 0.f;
  float ax2 = 0.f, ay2 = 0.f, ax3 = 0.f, ay3 = 0.f;
  float bx0 = 0.f, by0 = 0.f, bx1 = 0.f, by1 = 0.f;
  float bx2 = 0.f, by2 = 0.f, bx3 = 0.f, by3 = 0.f;
  for (int i = beg; i < end; i += 4) {
    int4   s4 = *(const int4*)&csr_src[i];
    float4 n4 = *(const float4*)&csr_norm[i];
    size_t o0 = (size_t)s4.x * 384, o1 = (size_t)s4.y * 384;
    size_t o2 = (size_t)s4.z * 384, o3 = (size_t)s4.w * 384;
    ushort2 v0 = *(const ushort2*)(base0 + o0);
    ushort2 v1 = *(const ushort2*)(base0 + o1);
    ushort2 v2 = *(const ushort2*)(base0 + o2);
    ushort2 v3 = *(const ushort2*)(base0 + o3);
    ushort2 u0 = *(const ushort2*)(base1 + o0);
    ushort2 u1 = *(const ushort2*)(base1 + o1);
    ushort2 u2 = *(const ushort2*)(base1 + o2);
    ushort2 u3 = *(const ushort2*)(base1 + o3);
    ax0 += n4.x * bf2f(v0.x); ay0 += n4.x * bf2f(v0.y);
    ax1 += n4.y * bf2f(v1.x); ay1 += n4.y * bf2f(v1.y);
    ax2 += n4.z * bf2f(v2.x); ay2 += n4.z * bf2f(v2.y);
    ax3 += n4.w * bf2f(v3.x); ay3 += n4.w * bf2f(v3.y);
    bx0 += n4.x * bf2f(u0.x); by0 += n4.x * bf2f(u0.y);
    bx1 += n4.y * bf2f(u1.x); by1 += n4.y * bf2f(u1.y);
    bx2 += n4.z * bf2f(u2.x); by2 += n4.z * bf2f(u2.y);
    bx3 += n4.w * bf2f(u3.x); by3 += n4.w * bf2f(u3.y);
  }
  float ax = (ax0 + ax1) + (ax2 + ax3);
  float ay = (ay0 + ay1) + (ay2 + ay3);
  float bx = (bx0 + bx1) + (bx2 + bx3);
  float by = (by0 + by1) + (by2 + by3);
  ushort2 oa; oa.x = f2bf(ax); oa.y = f2bf(ay);
  ushort2 ob; ob.x = f2bf(bx); ob.y = f2bf(by);
  *(ushort2*)&xcat[(size_t)(tp * B_N + b) * 384 + cout_ + lane * 2] = oa;
  *(ushort2*)&xcat[(size_t)((tp + 16) * B_N + b) * 384 + cout_ + lane * 2] = ob;
}

// ---------------- Kernel 6: MFMA triple-GEMM (K=384) + epilogue, direct [b][c][t] store ---------
// Wave M-tile = 16 timesteps of ONE sample b (thalf selects t0=0/16); cols 64 per chalf.
// Block = 8 waves = 8 consecutive b. Grid 1000 = 250 b-oct x {thalf,chalf}.
__global__ __launch_bounds__(512, 4) void k_gemm(
    const unsigned short* __restrict__ xcat, const unsigned short* __restrict__ wB,
    const float* __restrict__ tb, float* __restrict__ out)
{
  __shared__ unsigned short sB[24576];   // 48KB: 64 cols x 384 K, fragment-ordered
  const int tid = threadIdx.x;
  const int w = tid >> 6, lane = tid & 63;
  const int sel = blockIdx.x / 250;                  // 0..3
  const int b = (blockIdx.x % 250) * 8 + w;
  const int thalf = sel & 1, chalf = sel >> 1;
  const int t0 = thalf * 16;
  const int r = lane & 15, q = lane >> 4;

  const bf16x8* arow = (const bf16x8*)(xcat + (size_t)((t0 + r) * B_N + b) * 384 + q * 8);
  bf16x8 a[12];
  #pragma unroll
  for (int ks = 0; ks < 12; ++ks) a[ks] = arow[ks * 4];

  const float4* gB = (const float4*)(wB + (size_t)chalf * 24576);
  #pragma unroll
  for (int i = 0; i < 6; ++i) {
    int id = i * 512 + tid;
    ((float4*)sB)[id] = gB[id];
  }
  __syncthreads();

  f32x4 acc[4] = {};
  #pragma unroll
  for (int ks = 0; ks < 12; ++ks) {
    #pragma unroll
    for (int nf = 0; nf < 4; ++nf) {
      bf16x8 bv = *(const bf16x8*)&sB[((nf * 12 + ks) * 64 + lane) * 8];
      acc[nf] = __builtin_amdgcn_mfma_f32_16x16x32_bf16(a[ks], bv, acc[nf], 0, 0, 0);
    }
  }

  #pragma unroll
  for (int nf = 0; nf < 4; ++nf) {
    const int col = chalf * 64 + nf * 16 + r;
    const float bias = tb[col];
    float4 o;
    #pragma unroll
    for (int i = 0; i < 4; ++i) {
      const int t = t0 + q * 4 + i;
      float u = acc[nf][i] + bias;
      u = (u >= 0.f) ? u : NEG_S * u;
      float xv = bf2f(xcat[(size_t)(t * B_N + b) * 384 + col]);   // residual = xp
      ((float*)&o)[i] = xv + u;
    }
    *(float4*)&out[(size_t)b * 4096 + col * 32 + t0 + q * 4] = o;
  }
}

extern "C" void kernel_launch(void* const* d_in, const int* in_sizes, int n_in,
                              void* d_out, int out_size, void* d_ws, size_t ws_size,
                              hipStream_t stream)
{
  const float* x     = (const float*)d_in[0];
  const int*   ei    = (const int*)d_in[1];
  const float* ew    = (const float*)d_in[2];
  const float* cw    = (const float*)d_in[3];
  const float* cb    = (const float*)d_in[4];
  const float* gamma = (const float*)d_in[5];
  const float* beta  = (const float*)d_in[6];
  const float* tw    = (const float*)d_in[7];
  const float* tb    = (const float*)d_in[8];
  float* out = (float*)d_out;

  // workspace layout
  unsigned short* xcat = (unsigned short*)d_ws;                 // 64000*384 bf16
  float* deg = (float*)(xcat + (size_t)NNODE * 384);            // 2000 (16B aligned)
  int*   cnt    = (int*)(deg + B_N);                            // 2000
  int*   cursor = cnt + B_N;                                    // 2000
  int*   offs   = cursor + B_N;                                 // 2004 (padded for 16B align)
  int*   csr_src = offs + (B_N + 4);                            // EPAD_N
  float* csr_norm = (float*)(csr_src + EPAD_N);                 // EPAD_N
  unsigned short* wBc = (unsigned short*)(csr_norm + EPAD_N);   // 12288 bf16 frag-order
  unsigned short* wB  = wBc + 12288;                            // 49152 bf16 frag-order

  k_prep<<<96, 256, 0, stream>>>(cw, tw, wBc, wB, (int4*)deg);
  k_convln<<<500, 512, 0, stream>>>(x, wBc, cb, gamma, beta, xcat);
  k_deg<<<(E_N + 255) / 256, 256, 0, stream>>>(ei, ew, deg, cnt);
  k_scan<<<1, 256, 0, stream>>>(cnt, offs);
  k_scatter<<<(E_N + 255) / 256, 256, 0, stream>>>(ei, ew, deg, offs, cursor, csr_src, csr_norm);
  k_prop<<<B_N * 16 / 4, 256, 0, stream>>>(xcat, 0, 128, offs, csr_src, csr_norm);
  k_prop<<<B_N * 16 / 4, 256, 0, stream>>>(xcat, 128, 256, offs, csr_src, csr_norm);
  k_gemm<<<1000, 512, 0, stream>>>(xcat, wB, tb, out);
}

// Round 12
// 122.675 us; speedup vs baseline: 1.6757x; 1.0057x over previous
//
#include <hip/hip_runtime.h>
#include <hip/hip_bf16.h>
#include <math.h>

#define B_N   2000
#define T_N   32
#define CIN_N 32
#define COUT_N 128
#define E_N   32000
#define NEG_S 0.01f
#define EPS_S 1e-5f
#define NNODE (B_N * T_N)   // 64000
#define EPAD_N 38016        // padded CSR capacity (multiple-of-4 per node)
// contiguous meta region: deg(2000)+cnt(2000)+cursor(2000)+offs(2004)+csr_src(38016)+csr_norm(38016)
#define META_I4 21009       // 336144 B = 21009 int4

typedef __attribute__((ext_vector_type(8))) __bf16 bf16x8;
typedef __attribute__((ext_vector_type(4))) float f32x4;
typedef __attribute__((ext_vector_type(8))) unsigned short u16x8;

__device__ __forceinline__ unsigned short f2bf(float f) {
  unsigned u = __builtin_bit_cast(unsigned, f);
  u += 0x7FFFu + ((u >> 16) & 1u);   // RNE (finite values)
  return (unsigned short)(u >> 16);
}
__device__ __forceinline__ float bf2f(unsigned short h) {
  unsigned u = ((unsigned)h) << 16;
  return __builtin_bit_cast(float, u);
}

// ---------------- Kernel P: fused prep — zero meta + cast both weight tensors ----------------
// wBc[((nf2*3+ks)*64+lane)*8+e]  = cw[col*96+k],            col=nf2*16+(lane&15), k=ks*32+(lane>>4)*8+e
// wB [((nf2*12+ks)*64+lane)*8+e] = tag_w[k>>7][k&127][col], same lane mapping, K=384
__global__ __launch_bounds__(256) void k_prep(
    const float* __restrict__ cw, const float* __restrict__ tw,
    unsigned short* __restrict__ wBc, unsigned short* __restrict__ wB,
    int4* __restrict__ meta)
{
  const int tid0 = blockIdx.x * 256 + threadIdx.x;
  const int stride = gridDim.x * 256;
  const int4 z = {0, 0, 0, 0};
  for (int i = tid0; i < META_I4; i += stride) meta[i] = z;
  for (int idx = tid0; idx < 12288; idx += stride) {
    int e = idx & 7, lane = (idx >> 3) & 63, rest = idx >> 9;
    int ks = rest % 3, nf2 = rest / 3;
    int col = nf2 * 16 + (lane & 15);
    int k = ks * 32 + ((lane >> 4) << 3) + e;
    wBc[idx] = f2bf(cw[col * 96 + k]);
  }
  for (int idx = tid0; idx < 49152; idx += stride) {
    int e = idx & 7, lane = (idx >> 3) & 63, rest = idx >> 9;
    int ks = rest % 12, nf2 = rest / 12;
    int col = nf2 * 16 + (lane & 15);
    int k = ks * 32 + ((lane >> 4) << 3) + e;
    wB[idx] = f2bf(tw[(k >> 7) * 16384 + (k & 127) * 128 + col]);
  }
}

// ---------------- Kernel 1: FUSED causal-conv (MFMA) + bias + LeakyReLU + LayerNorm ----------
// Block = 4 samples x 2 waves; wave = 16 timesteps (t0=0/16) x 128 cols of one sample b.
// Writes x0[b][t][c] (b-major compact layout).
__global__ __launch_bounds__(512, 4) void k_convln(
    const float* __restrict__ x, const unsigned short* __restrict__ wBc,
    const float* __restrict__ cb, const float* __restrict__ gamma,
    const float* __restrict__ beta, unsigned short* __restrict__ x0)
{
  __shared__ unsigned short sB[12288];   // 24KB conv weights, frag-order
  __shared__ float sx4[4][1088];         // 17KB: per-sample im2col source, sx4[s][ci*34+t+2]
  __shared__ float red1[8], red2[8];
  const int tid = threadIdx.x;
  const int w = tid >> 6, lane = tid & 63;
  const int s = w >> 1;                       // sample slot 0..3
  const int b = blockIdx.x * 4 + s;
  const int t0 = (w & 1) * 16;
  const int r = lane & 15, q = lane >> 4;

  #pragma unroll
  for (int i = 0; i < 3; ++i) {
    int id = i * 512 + tid;                   // 1536 float4
    ((float4*)sB)[id] = ((const float4*)wBc)[id];
  }
  for (int idx = tid; idx < 4 * 1088; idx += 512) {
    int ss = idx / 1088;
    int rem = idx - ss * 1088;
    int ci = rem / 34, tt = rem - ci * 34;
    sx4[ss][rem] = (tt >= 2) ? x[(blockIdx.x * 4 + ss) * 1024 + ci * 32 + (tt - 2)] : 0.f;
  }
  __syncthreads();

  // build 3 A-fragments from LDS: A[t][k], t = t0+r, k = ks*32 + q*8 + e
  const int ta = t0 + r;
  u16x8 a_[3];
  #pragma unroll
  for (int ks = 0; ks < 3; ++ks) {
    #pragma unroll
    for (int e = 0; e < 8; ++e) {
      int k = ks * 32 + q * 8 + e;
      int ci = k / 3, kk = k - ci * 3;
      a_[ks][e] = f2bf(sx4[s][ci * 34 + ta + kk]);
    }
  }

  f32x4 acc[8] = {};
  #pragma unroll
  for (int ks = 0; ks < 3; ++ks) {
    bf16x8 a = __builtin_bit_cast(bf16x8, a_[ks]);
    #pragma unroll
    for (int nf = 0; nf < 8; ++nf) {
      bf16x8 bv = *(const bf16x8*)&sB[((nf * 3 + ks) * 64 + lane) * 8];
      acc[nf] = __builtin_amdgcn_mfma_f32_16x16x32_bf16(a, bv, acc[nf], 0, 0, 0);
    }
  }

  // bias + LeakyReLU in place; accumulate LN partials
  float s1 = 0.f, s2 = 0.f;
  #pragma unroll
  for (int nf = 0; nf < 8; ++nf) {
    const float bias = cb[nf * 16 + r];
    #pragma unroll
    for (int i = 0; i < 4; ++i) {
      float u = acc[nf][i] + bias;
      u = (u >= 0.f) ? u : NEG_S * u;
      acc[nf][i] = u;
      s1 += u; s2 += u * u;
    }
  }
  #pragma unroll
  for (int d = 32; d > 0; d >>= 1) {
    s1 += __shfl_down(s1, d);
    s2 += __shfl_down(s2, d);
  }
  if (lane == 0) { red1[w] = s1; red2[w] = s2; }
  __syncthreads();
  const float a1 = red1[w & ~1] + red1[w | 1];
  const float a2 = red2[w & ~1] + red2[w | 1];
  const float mu = a1 / 4096.f;
  const float rs = rsqrtf(a2 / 4096.f - mu * mu + EPS_S);

  // normalize + affine, write bf16 x0[b][t][col]
  #pragma unroll
  for (int nf = 0; nf < 8; ++nf) {
    const int col = nf * 16 + r;
    #pragma unroll
    for (int i = 0; i < 4; ++i) {
      const int t = t0 + q * 4 + i;
      float v = (acc[nf][i] - mu) * rs * gamma[col * 32 + t] + beta[col * 32 + t];
      x0[((size_t)b * 32 + t) * 128 + col] = f2bf(v);
    }
  }
}

// ---------------- Kernel 2: in-degree (weighted) + in-edge counts ----------------
__global__ void k_deg(const int* __restrict__ ei, const float* __restrict__ ew,
                      float* __restrict__ deg, int* __restrict__ cnt)
{
  int e = blockIdx.x * 256 + threadIdx.x;
  if (e >= E_N) return;
  int d = ei[E_N + e];
  atomicAdd(&deg[d], ew[e]);
  atomicAdd(&cnt[d], 1);
}

// ---------------- Kernel 3: single-block exclusive scan over 2000 PADDED counts ----------------
__global__ __launch_bounds__(256) void k_scan(const int* __restrict__ cnt, int* __restrict__ offs)
{
  __shared__ int wsum[4];
  int tid = threadIdx.x;
  int vals[8];
  int run = 0;
  #pragma unroll
  for (int i = 0; i < 8; ++i) {
    int idx = tid * 8 + i;
    vals[i] = run;
    int v = (idx < B_N) ? cnt[idx] : 0;
    v = (v + 3) & ~3;                       // pad to multiple of 4
    run += v;
  }
  int lane = tid & 63, wid = tid >> 6;
  int xs = run;
  #pragma unroll
  for (int d = 1; d < 64; d <<= 1) {
    int y = __shfl_up(xs, d);
    if (lane >= d) xs += y;
  }
  if (lane == 63) wsum[wid] = xs;
  __syncthreads();
  int pre = 0;
  for (int w = 0; w < wid; ++w) pre += wsum[w];
  int excl = pre + xs - run;
  #pragma unroll
  for (int i = 0; i < 8; ++i) {
    int idx = tid * 8 + i;
    if (idx <= B_N) offs[idx] = excl + vals[i];
  }
}

// ---------------- Kernel 4: CSR scatter + edge norm (pad slots stay {src=0, norm=0}) ----------------
__global__ void k_scatter(const int* __restrict__ ei, const float* __restrict__ ew,
                          const float* __restrict__ deg, const int* __restrict__ offs,
                          int* __restrict__ cursor, int* __restrict__ csr_src,
                          float* __restrict__ csr_norm)
{
  int e = blockIdx.x * 256 + threadIdx.x;
  if (e >= E_N) return;
  int s = ei[e], d = ei[E_N + e];
  float ds_ = deg[s], dd = deg[d];
  float dis_s = (ds_ > 0.f) ? rsqrtf(fmaxf(ds_, 1e-12f)) : 0.f;
  float dis_d = (dd  > 0.f) ? rsqrtf(fmaxf(dd,  1e-12f)) : 0.f;
  float nrm = dis_s * ew[e] * dis_d;
  int pos = offs[d] + atomicAdd(&cursor[d], 1);
  csr_src[pos] = s;
  csr_norm[pos] = nrm;
}

// ---------------- Kernel 5: one-hop propagation, b-major layout, wide contiguous loads --------
// Wave = (dst b, t-quarter tq in 0..7): per edge read hin[src][tq*4..+4][128] = 1KB contiguous
// (one b128 per lane). 16000 waves; read band/tq = 2MB (L2-fit). Lane: t=tq*4+(l>>4), c=(l&15)*8.
__global__ __launch_bounds__(256) void k_prop(
    const unsigned short* __restrict__ hin, unsigned short* __restrict__ hout,
    const int* __restrict__ offs, const int* __restrict__ csr_src,
    const float* __restrict__ csr_norm)
{
  int gw = (blockIdx.x * 256 + threadIdx.x) >> 6;
  int lane = threadIdx.x & 63;
  if (gw >= B_N * 8) return;
  int tq = gw / B_N;                 // 0..7
  int b  = gw - tq * B_N;
  int beg = offs[b], end = offs[b + 1];           // both multiples of 4
  const size_t lelem = (size_t)(tq * 4 + (lane >> 4)) * 128 + (lane & 15) * 8;
  float acc[8] = {};
  for (int i = beg; i < end; i += 4) {
    int4   s4 = *(const int4*)&csr_src[i];
    float4 n4 = *(const float4*)&csr_norm[i];
    u16x8 v0 = *(const u16x8*)&hin[(size_t)s4.x * 4096 + lelem];
    u16x8 v1 = *(const u16x8*)&hin[(size_t)s4.y * 4096 + lelem];
    u16x8 v2 = *(const u16x8*)&hin[(size_t)s4.z * 4096 + lelem];
    u16x8 v3 = *(const u16x8*)&hin[(size_t)s4.w * 4096 + lelem];
    #pragma unroll
    for (int e = 0; e < 8; ++e) {
      acc[e] += n4.x * bf2f(v0[e]) + n4.y * bf2f(v1[e])
              + n4.z * bf2f(v2[e]) + n4.w * bf2f(v3[e]);
    }
  }
  u16x8 o;
  #pragma unroll
  for (int e = 0; e < 8; ++e) o[e] = f2bf(acc[e]);
  *(u16x8*)&hout[(size_t)b * 4096 + lelem] = o;
}

// ---------------- Kernel 6: MFMA triple-GEMM (K=384) + epilogue, direct [b][c][t] store ---------
// Wave M-tile = 16 timesteps of ONE sample b; A-frags from x0/h1/h2 (4 each); cols 64 per chalf.
__global__ __launch_bounds__(512, 4) void k_gemm(
    const unsigned short* __restrict__ x0, const unsigned short* __restrict__ h1,
    const unsigned short* __restrict__ h2, const unsigned short* __restrict__ wB,
    const float* __restrict__ tb, float* __restrict__ out)
{
  __shared__ unsigned short sB[24576];   // 48KB: 64 cols x 384 K, fragment-ordered
  const int tid = threadIdx.x;
  const int w = tid >> 6, lane = tid & 63;
  const int sel = blockIdx.x / 250;                  // 0..3
  const int b = (blockIdx.x % 250) * 8 + w;
  const int thalf = sel & 1, chalf = sel >> 1;
  const int t0 = thalf * 16;
  const int r = lane & 15, q = lane >> 4;

  // 12 A-fragments: ks 0..3 from x0, 4..7 from h1, 8..11 from h2
  const size_t abase = ((size_t)b * 32 + t0 + r) * 128 + q * 8;
  bf16x8 a[12];
  #pragma unroll
  for (int ks = 0; ks < 12; ++ks) {
    const unsigned short* arr = (ks < 4) ? x0 : (ks < 8) ? h1 : h2;
    a[ks] = *(const bf16x8*)&arr[abase + (size_t)(ks & 3) * 32];
  }

  const float4* gB = (const float4*)(wB + (size_t)chalf * 24576);
  #pragma unroll
  for (int i = 0; i < 6; ++i) {
    int id = i * 512 + tid;
    ((float4*)sB)[id] = gB[id];
  }
  __syncthreads();

  f32x4 acc[4] = {};
  #pragma unroll
  for (int ks = 0; ks < 12; ++ks) {
    #pragma unroll
    for (int nf = 0; nf < 4; ++nf) {
      bf16x8 bv = *(const bf16x8*)&sB[((nf * 12 + ks) * 64 + lane) * 8];
      acc[nf] = __builtin_amdgcn_mfma_f32_16x16x32_bf16(a[ks], bv, acc[nf], 0, 0, 0);
    }
  }

  #pragma unroll
  for (int nf = 0; nf < 4; ++nf) {
    const int col = chalf * 64 + nf * 16 + r;
    const float bias = tb[col];
    float4 o;
    #pragma unroll
    for (int i = 0; i < 4; ++i) {
      const int t = t0 + q * 4 + i;
      float u = acc[nf][i] + bias;
      u = (u >= 0.f) ? u : NEG_S * u;
      float xv = bf2f(x0[((size_t)b * 32 + t) * 128 + col]);   // residual = xp
      ((float*)&o)[i] = xv + u;
    }
    *(float4*)&out[(size_t)b * 4096 + col * 32 + t0 + q * 4] = o;
  }
}

extern "C" void kernel_launch(void* const* d_in, const int* in_sizes, int n_in,
                              void* d_out, int out_size, void* d_ws, size_t ws_size,
                              hipStream_t stream)
{
  const float* x     = (const float*)d_in[0];
  const int*   ei    = (const int*)d_in[1];
  const float* ew    = (const float*)d_in[2];
  const float* cw    = (const float*)d_in[3];
  const float* cb    = (const float*)d_in[4];
  const float* gamma = (const float*)d_in[5];
  const float* beta  = (const float*)d_in[6];
  const float* tw    = (const float*)d_in[7];
  const float* tb    = (const float*)d_in[8];
  float* out = (float*)d_out;

  // workspace layout: three b-major feature arrays [b][32][128] bf16
  unsigned short* x0 = (unsigned short*)d_ws;                   // 64000*128 bf16
  unsigned short* h1 = x0 + (size_t)NNODE * 128;                // 64000*128 bf16
  unsigned short* h2 = h1 + (size_t)NNODE * 128;                // 64000*128 bf16
  float* deg = (float*)(h2 + (size_t)NNODE * 128);              // 2000 (16B aligned)
  int*   cnt    = (int*)(deg + B_N);                            // 2000
  int*   cursor = cnt + B_N;                                    // 2000
  int*   offs   = cursor + B_N;                                 // 2004 (padded for 16B align)
  int*   csr_src = offs + (B_N + 4);                            // EPAD_N
  float* csr_norm = (float*)(csr_src + EPAD_N);                 // EPAD_N
  unsigned short* wBc = (unsigned short*)(csr_norm + EPAD_N);   // 12288 bf16 frag-order
  unsigned short* wB  = wBc + 12288;                            // 49152 bf16 frag-order

  k_prep<<<96, 256, 0, stream>>>(cw, tw, wBc, wB, (int4*)deg);
  k_convln<<<500, 512, 0, stream>>>(x, wBc, cb, gamma, beta, x0);
  k_deg<<<(E_N + 255) / 256, 256, 0, stream>>>(ei, ew, deg, cnt);
  k_scan<<<1, 256, 0, stream>>>(cnt, offs);
  k_scatter<<<(E_N + 255) / 256, 256, 0, stream>>>(ei, ew, deg, offs, cursor, csr_src, csr_norm);
  k_prop<<<B_N * 8 / 4, 256, 0, stream>>>(x0, h1, offs, csr_src, csr_norm);
  k_prop<<<B_N * 8 / 4, 256, 0, stream>>>(h1, h2, offs, csr_src, csr_norm);
  k_gemm<<<1000, 512, 0, stream>>>(x0, h1, h2, wB, tb, out);
}